// Round 3
// baseline (685.623 us; speedup 1.0000x reference)
//
#include <hip/hip_runtime.h>
#include <hip/hip_bf16.h>

typedef __attribute__((ext_vector_type(8))) short bf16x8;
typedef __attribute__((ext_vector_type(4))) float f32x4;

#define MFMA16(a, b, c) __builtin_amdgcn_mfma_f32_16x16x32_bf16((a), (b), (c), 0, 0, 0)

#define N_ 64
#define C_ 192
#define T_ 128
#define V_ 25
#define S_ 3
#define MID 64
#define TV 3200          // T_*V_
#define C3 576           // 3*C_
#define OUT_ELEMS 39321600ULL
#define NCHUNK 16        // T-chunks for k2 partials
#define PSTRIDE 640      // padded 25*25 partial stride (floats)

static __device__ __forceinline__ float bf2f(ushort u) {
    union { unsigned int i; float f; } x; x.i = ((unsigned int)u) << 16; return x.f;
}
static __device__ __forceinline__ ushort f2bf(float f) {
    union { float f; unsigned int i; } x; x.f = f;
    unsigned int r = x.i + 0x7fffu + ((x.i >> 16) & 1u);
    return (ushort)(r >> 16);
}
static __device__ __forceinline__ unsigned int pack2(float a, float b) {
    return (unsigned int)f2bf(a) | ((unsigned int)f2bf(b) << 16);
}

// ---------------------------------------------------------------------------
// kconv: fp32 -> bf16 row-major copy (weights). n4 = number of float4 chunks.
// ---------------------------------------------------------------------------
__global__ __launch_bounds__(256) void kconv(const float* __restrict__ src,
                                             ushort* __restrict__ dst, int n4) {
    int i = blockIdx.x * 256 + threadIdx.x;
    if (i < n4) {
        float4 d = *(const float4*)(src + (size_t)i * 4);
        unsigned int* o = (unsigned int*)dst + (size_t)i * 2;
        o[0] = pack2(d.x, d.y);
        o[1] = pack2(d.z, d.w);
    }
}

// ---------------------------------------------------------------------------
// K1: qkvT[n][m][o] = sum_k x[n][k][m] * Wqkv[o][k] + bqkv[o]   (bf16 out)
// m-tile 64, grid (50,64)=3200 blocks, LDS ~53.5KB -> 3 blocks/CU.
// Async W-prefetch (T14): next tile's B held in 6 uint4 regs during current
// tile's MFMA, ds_written at loop top -> L2 latency off the barrier-critical
// path. Bias staged once for all 576 outputs.
// ---------------------------------------------------------------------------
__global__ __launch_bounds__(256) void k1_qkv(const float* __restrict__ x,
                                              const ushort* __restrict__ Wbf,
                                              const float* __restrict__ bias,
                                              ushort* __restrict__ qkvT) {
    int m0 = blockIdx.x * 64, n = blockIdx.y;
    __shared__ ushort As[64 * 200];    // [m][c], c stride 200 shorts
    __shared__ ushort Bs[64 * 200];    // [o][c]; front 13.4KB aliased as scratch
    __shared__ float biasS[C3];
    unsigned int* scratchU = (unsigned int*)Bs;   // 96 rows x 35 dwords (odd stride)
    ushort* scratchS = Bs;                        // same, short view: row stride 70
    int tid = threadIdx.x;

    // per-thread W staging geometry (constant across tiles) + tile-0 prefetch
    int wr[6], wc[6];
    uint4 w[6];
#pragma unroll
    for (int j = 0; j < 6; j++) {
        int chunk = tid + j * 256;          // 1536 = 64 rows * 24 uint4
        wr[j] = chunk / 24; wc[j] = (chunk % 24) * 8;
        w[j] = *(const uint4*)(Wbf + (size_t)wr[j] * C_ + wc[j]);
    }
    for (int i = tid; i < C3; i += 256) biasS[i] = bias[i];

    // ---- stage A: 2 groups of 96 channels (fused fp32->bf16 transpose) ----
    for (int cg = 0; cg < 2; cg++) {
        if (cg) __syncthreads();       // transpose reads of scratch done
#pragma unroll
        for (int j = 0; j < 6; j++) {
            int chunk = tid + j * 256;          // 1536 = 96c * 16 f4
            int cc = chunk >> 4, m4 = chunk & 15;
            float4 d = *(const float4*)(x + ((size_t)n * C_ + cg * 96 + cc) * TV + m0 + m4 * 4);
            scratchU[cc * 35 + m4 * 2]     = pack2(d.x, d.y);
            scratchU[cc * 35 + m4 * 2 + 1] = pack2(d.z, d.w);
        }
        __syncthreads();
#pragma unroll
        for (int j = 0; j < 24; j++) {
            int idx = tid + j * 256;            // 6144 = 64m * 96c
            int mm = idx / 96, cc = idx % 96;
            As[mm * 200 + cg * 96 + cc] = scratchS[cc * 70 + mm];
        }
    }

    int wave = tid >> 6, lane = tid & 63;
    int mb = (wave >> 1) * 32, ob = (wave & 1) * 32;
    int lrow = lane & 15, lk = lane >> 4;

    // ---- loop over 9 o-tiles, software-pipelined B ----
    for (int oi = 0; oi < 9; oi++) {
        int o0 = oi * 64;
        __syncthreads();               // scratch reads / prev MFMA Bs reads done
#pragma unroll
        for (int j = 0; j < 6; j++)
            *(uint4*)&Bs[wr[j] * 200 + wc[j]] = w[j];
        if (oi < 8) {
#pragma unroll
            for (int j = 0; j < 6; j++)
                w[j] = *(const uint4*)(Wbf + (size_t)(o0 + 64 + wr[j]) * C_ + wc[j]);
        }
        __syncthreads();

        f32x4 acc[2][2];
#pragma unroll
        for (int i = 0; i < 2; i++)
#pragma unroll
            for (int j = 0; j < 2; j++) acc[i][j] = (f32x4){0.f, 0.f, 0.f, 0.f};

#pragma unroll
        for (int ks = 0; ks < 6; ks++) {
            bf16x8 a[2], b[2];
#pragma unroll
            for (int mt = 0; mt < 2; mt++)
                a[mt] = *(const bf16x8*)&As[(mb + mt * 16 + lrow) * 200 + ks * 32 + lk * 8];
#pragma unroll
            for (int ot = 0; ot < 2; ot++)
                b[ot] = *(const bf16x8*)&Bs[(ob + ot * 16 + lrow) * 200 + ks * 32 + lk * 8];
#pragma unroll
            for (int mt = 0; mt < 2; mt++)
#pragma unroll
                for (int ot = 0; ot < 2; ot++)
                    acc[mt][ot] = MFMA16(a[mt], b[ot], acc[mt][ot]);
        }

        ushort* op = qkvT + ((size_t)n * TV + m0) * C3 + o0;
#pragma unroll
        for (int mt = 0; mt < 2; mt++) {
#pragma unroll
            for (int ot = 0; ot < 2; ot++) {
                int o = ob + ot * 16 + lrow;
                float bv = biasS[o0 + o];
#pragma unroll
                for (int r = 0; r < 4; r++) {
                    int m = mb + mt * 16 + lk * 4 + r;
                    op[(size_t)m * C3 + o] = f2bf(acc[mt][ot][r] + bv);
                }
            }
        }
    }
}

// ---------------------------------------------------------------------------
// K2p: partial[((n*3+s)*16+tc)][u][v] = sum over 8 t's of q.k  (fp32)
// grid (16,3,64) = 3072 blocks. MFMA fragments loaded DIRECTLY from global
// (frag addresses map to contiguous 16B chunks; rows >=25 zero-selected).
// No Q/K LDS, no barriers in the load path; LDS only for cross-wave red
// (16.9KB) -> ~5+ blocks/CU, 16 independent loads in flight per wave.
// ---------------------------------------------------------------------------
__global__ __launch_bounds__(256) void k2_att(const ushort* __restrict__ qkvT,
                                              float* __restrict__ partial) {
    int tc = blockIdx.x, s = blockIdx.y, n = blockIdx.z;
    __shared__ float red[4 * 32 * 33];
    int tid = threadIdx.x, wave = tid >> 6, lane = tid & 63;
    int lrow = lane & 15, lk = lane >> 4;

    const size_t nbase = (size_t)n * TV * C3;
    int qoff = s * MID;
    int koff = C_ + s * MID;

    int r1 = 16 + lrow;
    int r1c = (r1 < V_) ? r1 : (V_ - 1);   // clamped (in-bounds) row for upper tile
    bool r1ok = r1 < V_;
    bf16x8 zv = {0, 0, 0, 0, 0, 0, 0, 0};

    f32x4 acc[2][2];
#pragma unroll
    for (int i = 0; i < 2; i++)
#pragma unroll
        for (int j = 0; j < 2; j++) acc[i][j] = (f32x4){0.f, 0.f, 0.f, 0.f};

#pragma unroll
    for (int i = 0; i < 2; i++) {
        int t = tc * 8 + wave + 4 * i;
        const ushort* base0 = qkvT + nbase + (size_t)(t * V_ + lrow) * C3;
        const ushort* base1 = qkvT + nbase + (size_t)(t * V_ + r1c) * C3;
#pragma unroll
        for (int ks = 0; ks < 2; ks++) {
            int co = ks * 32 + lk * 8;
            bf16x8 a0 = *(const bf16x8*)(base0 + qoff + co);
            bf16x8 b0 = *(const bf16x8*)(base0 + koff + co);
            bf16x8 a1 = *(const bf16x8*)(base1 + qoff + co);
            bf16x8 b1 = *(const bf16x8*)(base1 + koff + co);
            a1 = r1ok ? a1 : zv;
            b1 = r1ok ? b1 : zv;
            acc[0][0] = MFMA16(a0, b0, acc[0][0]);
            acc[0][1] = MFMA16(a0, b1, acc[0][1]);
            acc[1][0] = MFMA16(a1, b0, acc[1][0]);
            acc[1][1] = MFMA16(a1, b1, acc[1][1]);
        }
    }

#pragma unroll
    for (int ub = 0; ub < 2; ub++)
#pragma unroll
        for (int vb = 0; vb < 2; vb++)
#pragma unroll
            for (int r = 0; r < 4; r++) {
                int u = ub * 16 + lk * 4 + r, v = vb * 16 + lrow;
                red[wave * 1056 + u * 33 + v] = acc[ub][vb][r];
            }
    __syncthreads();

    float* pb = partial + (((size_t)n * S_ + s) * NCHUNK + tc) * PSTRIDE;
    for (int idx = tid; idx < 1024; idx += 256) {
        int u = idx >> 5, v = idx & 31;
        if (u < V_ && v < V_) {
            float sum = red[u * 33 + v] + red[1056 + u * 33 + v] +
                        red[2112 + u * 33 + v] + red[3168 + u * 33 + v];
            pb[u * V_ + v] = sum;
        }
    }
}

// ---------------------------------------------------------------------------
// K2r: attOut[ns][r] = tanh(sum_j partial[ns][j][r] / 8192)
// ---------------------------------------------------------------------------
__global__ __launch_bounds__(256) void k2_reduce(const float* __restrict__ partial,
                                                 float* __restrict__ attOut) {
    int idx = blockIdx.x * 256 + threadIdx.x;
    if (idx >= 192 * 625) return;
    int ns = idx / 625, r = idx % 625;
    const float* p = partial + (size_t)ns * NCHUNK * PSTRIDE + r;
    float s = 0.f;
#pragma unroll
    for (int j = 0; j < NCHUNK; j++) s += p[j * PSTRIDE];
    attOut[(size_t)ns * 625 + r] = tanhf(s * (1.0f / 8192.0f));
}

// ---------------------------------------------------------------------------
// K3: yT[n][t*25+u][c'] = sum_v att[n][s(c')][u][v] * qkv_v[n][t*25+v][c']
// att pointer made provably wave-uniform via readfirstlane -> scalar (K$)
// loads instead of 625 LDS broadcast reads/thread. No LDS, no sync.
// ---------------------------------------------------------------------------
__global__ __launch_bounds__(192) void k3_y(const ushort* __restrict__ qkvT,
                                            const float* __restrict__ attF,
                                            ushort* __restrict__ yT) {
    int t = blockIdx.x, n = blockIdx.y;
    int tid = threadIdx.x;
    int c = tid;
    int s = __builtin_amdgcn_readfirstlane(tid >> 6);   // wave-uniform subset id
    const float* as = attF + ((size_t)n * S_ + s) * 625;

    const ushort* vb = qkvT + ((size_t)n * TV + (size_t)t * V_) * C3 + 2 * C_ + c;
    float vreg[25];
#pragma unroll
    for (int v = 0; v < 25; v++) vreg[v] = bf2f(vb[(size_t)v * C3]);

    ushort* yb = yT + ((size_t)n * TV + (size_t)t * V_) * C_ + c;
    for (int u = 0; u < 25; u++) {
        float a = 0.f;
#pragma unroll
        for (int v = 0; v < 25; v++) a += as[u * 25 + v] * vreg[v];
        yb[(size_t)u * C_] = f2bf(a);
    }
}

// ---------------------------------------------------------------------------
// K4: out[n][o][m] = LeakyReLU(x + (yT.Wff^T)*inv[o] + shift[o], 0.1)  fp32
// m-tile 64, A staged once, 3 o-tiles. Async W-prefetch like k1; BN constants
// hoisted out of the loop; x-tile loads issued before the zT phase so their
// latency hides under the epilogue VALU. LDS ~52.8KB -> 3 blocks/CU.
// ---------------------------------------------------------------------------
__global__ __launch_bounds__(256) void k4_out(const ushort* __restrict__ yT,
                                              const ushort* __restrict__ Wbf,
                                              const float* __restrict__ bff,
                                              const float* __restrict__ gamma,
                                              const float* __restrict__ beta,
                                              const float* __restrict__ rmean,
                                              const float* __restrict__ rvar,
                                              const float* __restrict__ x,
                                              float* __restrict__ out) {
    int m0 = blockIdx.x * 64, n = blockIdx.y;
    __shared__ ushort As[64 * 200];
    __shared__ ushort Bs[64 * 200];    // 25.6KB; reused as fp32 zT[64][68] (17.4KB)
    __shared__ float invS[C_], shiftS[C_];
    float* zT = (float*)Bs;
    int tid = threadIdx.x;

    // per-thread W staging geometry + tile-0 prefetch
    int wr[6], wc[6];
    uint4 w[6];
#pragma unroll
    for (int j = 0; j < 6; j++) {
        int chunk = tid + j * 256;
        wr[j] = chunk / 24; wc[j] = (chunk % 24) * 8;
        w[j] = *(const uint4*)(Wbf + (size_t)wr[j] * C_ + wc[j]);
    }

    const ushort* ab = yT + ((size_t)n * TV + m0) * C_;
#pragma unroll
    for (int j = 0; j < 6; j++) {
        int chunk = tid + j * 256;          // 1536 = 64 rows * 24 chunks
        int r = chunk / 24, c8 = chunk % 24;
        *(uint4*)&As[r * 200 + c8 * 8] = *(const uint4*)(ab + (size_t)r * C_ + c8 * 8);
    }
    if (tid < C_) {
        float inv = gamma[tid] * rsqrtf(rvar[tid] + 1e-5f);
        invS[tid] = inv;
        shiftS[tid] = beta[tid] - rmean[tid] * inv + bff[tid] * inv;
    }

    int wave = tid >> 6, lane = tid & 63;
    int mb = (wave >> 1) * 32, obw = (wave & 1) * 32;
    int lrow = lane & 15, lk = lane >> 4;

    for (int oi = 0; oi < 3; oi++) {
        int o0 = oi * 64;
        __syncthreads();               // As/invS staged, prev epilogue zT reads done
#pragma unroll
        for (int j = 0; j < 6; j++)
            *(uint4*)&Bs[wr[j] * 200 + wc[j]] = w[j];
        if (oi < 2) {
#pragma unroll
            for (int j = 0; j < 6; j++)
                w[j] = *(const uint4*)(Wbf + (size_t)(o0 + 64 + wr[j]) * C_ + wc[j]);
        }
        __syncthreads();

        f32x4 acc[2][2];
#pragma unroll
        for (int i = 0; i < 2; i++)
#pragma unroll
            for (int j = 0; j < 2; j++) acc[i][j] = (f32x4){0.f, 0.f, 0.f, 0.f};

#pragma unroll
        for (int ks = 0; ks < 6; ks++) {
            bf16x8 a[2], b[2];
#pragma unroll
            for (int mt = 0; mt < 2; mt++)
                a[mt] = *(const bf16x8*)&As[(mb + mt * 16 + lrow) * 200 + ks * 32 + lk * 8];
#pragma unroll
            for (int ot = 0; ot < 2; ot++)
                b[ot] = *(const bf16x8*)&Bs[(obw + ot * 16 + lrow) * 200 + ks * 32 + lk * 8];
#pragma unroll
            for (int mt = 0; mt < 2; mt++)
#pragma unroll
                for (int ot = 0; ot < 2; ot++)
                    acc[mt][ot] = MFMA16(a[mt], b[ot], acc[mt][ot]);
        }

        __syncthreads();               // all waves done reading Bs (W)

        // issue x loads early: latency hides under zT-write VALU phase
        const float* xb = x + ((size_t)n * C_ + o0) * TV + m0;
        float* ob2 = out + ((size_t)n * C_ + o0) * TV + m0;
        float4 xv[4];
#pragma unroll
        for (int j = 0; j < 4; j++) {
            int chunk = tid + j * 256;
            int o = chunk >> 4, m4 = chunk & 15;
            xv[j] = *(const float4*)(xb + (size_t)o * TV + m4 * 4);
        }

#pragma unroll
        for (int mt = 0; mt < 2; mt++)
#pragma unroll
            for (int ot = 0; ot < 2; ot++) {
                int o = obw + ot * 16 + lrow;
                float inv = invS[o0 + o], sh = shiftS[o0 + o];
#pragma unroll
                for (int r = 0; r < 4; r++) {
                    int m = mb + mt * 16 + lk * 4 + r;
                    zT[o * 68 + m] = acc[mt][ot][r] * inv + sh;
                }
            }
        __syncthreads();

#pragma unroll
        for (int j = 0; j < 4; j++) {
            int chunk = tid + j * 256;          // 1024 = 64 rows * 16 f4
            int o = chunk >> 4, m4 = chunk & 15;
            float4 zv = *(float4*)&zT[o * 68 + m4 * 4];
            float4 res; float a;
            a = xv[j].x + zv.x; res.x = (a >= 0.f) ? a : 0.1f * a;
            a = xv[j].y + zv.y; res.y = (a >= 0.f) ? a : 0.1f * a;
            a = xv[j].z + zv.z; res.z = (a >= 0.f) ? a : 0.1f * a;
            a = xv[j].w + zv.w; res.w = (a >= 0.f) ? a : 0.1f * a;
            *(float4*)(ob2 + (size_t)o * TV + m4 * 4) = res;
        }
    }
}

// ---------------------------------------------------------------------------
extern "C" void kernel_launch(void* const* d_in, const int* in_sizes, int n_in,
                              void* d_out, int out_size, void* d_ws, size_t ws_size,
                              hipStream_t stream) {
    (void)in_sizes; (void)n_in; (void)out_size; (void)ws_size;
    const float* x    = (const float*)d_in[0];
    const float* Wqkv = (const float*)d_in[1];
    const float* bqkv = (const float*)d_in[2];
    const float* Wff  = (const float*)d_in[3];
    const float* bff  = (const float*)d_in[4];
    const float* gam  = (const float*)d_in[5];
    const float* bet  = (const float*)d_in[6];
    const float* rme  = (const float*)d_in[7];
    const float* rva  = (const float*)d_in[8];
    float* out = (float*)d_out;
    float* attOut = out + OUT_ELEMS;   // fp32 att segment of the output tuple

    char* ws = (char*)d_ws;
    ushort* qkvT = (ushort*)ws;                        // 235,929,600 B
    // partial (7.86 MB) and yT (78.6 MB) alias: partial is dead before k3 runs
    float*  partial = (float*)(ws + 235929600);
    ushort* yT      = (ushort*)(ws + 235929600);
    // WqkvB aliases the partial region: written by kconv, consumed by k1,
    // clobbered only later by k2_att's partial writes.
    ushort* WqkvB   = (ushort*)(ws + 235929600);
    // WffB aliases qkvT: qkvT is dead after k3 (k4 doesn't read it).
    ushort* WffB    = (ushort*)ws;

    kconv<<<dim3(108), 256, 0, stream>>>(Wqkv, WqkvB, 27648);   // 576*192/4
    k1_qkv<<<dim3(50, 64), 256, 0, stream>>>(x, WqkvB, bqkv, qkvT);
    k2_att<<<dim3(NCHUNK, 3, 64), 256, 0, stream>>>(qkvT, partial);
    k2_reduce<<<dim3(469), 256, 0, stream>>>(partial, attOut);
    k3_y<<<dim3(128, 64), 192, 0, stream>>>(qkvT, attOut, yT);
    kconv<<<dim3(36), 256, 0, stream>>>(Wff, WffB, 9216);       // 192*192/4
    k4_out<<<dim3(50, 64), 256, 0, stream>>>(yT, WffB, bff, gam, bet, rme, rva, x, out);
}

// Round 4
// 499.081 us; speedup vs baseline: 1.3738x; 1.3738x over previous
//
#include <hip/hip_runtime.h>
#include <hip/hip_bf16.h>

typedef __attribute__((ext_vector_type(8))) short bf16x8;
typedef __attribute__((ext_vector_type(4))) float f32x4;

#define MFMA16(a, b, c) __builtin_amdgcn_mfma_f32_16x16x32_bf16((a), (b), (c), 0, 0, 0)

#define N_ 64
#define C_ 192
#define T_ 128
#define V_ 25
#define S_ 3
#define MID 64
#define TV 3200          // T_*V_
#define C3 576           // 3*C_
#define OUT_ELEMS 39321600ULL
#define NCHUNK 16        // T-chunks for k2 partials
#define PSTRIDE 640      // padded 25*25 partial stride (floats)

static __device__ __forceinline__ float bf2f(ushort u) {
    union { unsigned int i; float f; } x; x.i = ((unsigned int)u) << 16; return x.f;
}
static __device__ __forceinline__ ushort f2bf(float f) {
    union { float f; unsigned int i; } x; x.f = f;
    unsigned int r = x.i + 0x7fffu + ((x.i >> 16) & 1u);
    return (ushort)(r >> 16);
}
static __device__ __forceinline__ unsigned int pack2(float a, float b) {
    return (unsigned int)f2bf(a) | ((unsigned int)f2bf(b) << 16);
}

// ---------------------------------------------------------------------------
// kconv: fp32 -> bf16 row-major copy (weights). n4 = number of float4 chunks.
// ---------------------------------------------------------------------------
__global__ __launch_bounds__(256) void kconv(const float* __restrict__ src,
                                             ushort* __restrict__ dst, int n4) {
    int i = blockIdx.x * 256 + threadIdx.x;
    if (i < n4) {
        float4 d = *(const float4*)(src + (size_t)i * 4);
        unsigned int* o = (unsigned int*)dst + (size_t)i * 2;
        o[0] = pack2(d.x, d.y);
        o[1] = pack2(d.z, d.w);
    }
}

// ---------------------------------------------------------------------------
// K1: qkvT[n][m][o] = sum_k x[n][k][m] * Wqkv[o][k] + bqkv[o]   (bf16 out)
// 512-thread blocks, TWO 64-row m-tiles sharing one Bs (waves 0-3 -> tile 0,
// waves 4-7 -> tile 1). LDS = 2xAs(25.6K) + Bs(25.6K) ~77KB -> 2 blocks/CU
// = 16 waves/CU (was 12): occupancy +33% and per-work W staging halved.
// Inner MFMA/epilogue identical to the verified R2 kernel. No cross-phase
// register prefetch (R3's spill regression).
// ---------------------------------------------------------------------------
__global__ __launch_bounds__(512) void k1_qkv(const float* __restrict__ x,
                                              const ushort* __restrict__ Wbf,
                                              const float* __restrict__ bias,
                                              ushort* __restrict__ qkvT) {
    int m0 = blockIdx.x * 128, n = blockIdx.y;
    __shared__ ushort As[2][64 * 200]; // [half][m][c], c stride 200 shorts
    __shared__ ushort Bs[64 * 200];    // [o][c]; front 13.4KB aliased as scratch
    __shared__ float biasS[64];
    unsigned int* scratchU = (unsigned int*)Bs;   // 96 rows x 35 dwords (odd stride)
    ushort* scratchS = Bs;                        // same, short view: row stride 70
    int tid = threadIdx.x;

    // ---- stage A: 2 halves x 2 groups of 96 channels ----
    for (int h = 0; h < 2; h++) {
        for (int cg = 0; cg < 2; cg++) {
            if (h || cg) __syncthreads();  // transpose reads of scratch done
#pragma unroll
            for (int j = 0; j < 3; j++) {
                int chunk = tid + j * 512;          // 1536 = 96c * 16 f4
                int cc = chunk >> 4, m4 = chunk & 15;
                float4 d = *(const float4*)(x + ((size_t)n * C_ + cg * 96 + cc) * TV
                                            + m0 + h * 64 + m4 * 4);
                scratchU[cc * 35 + m4 * 2]     = pack2(d.x, d.y);
                scratchU[cc * 35 + m4 * 2 + 1] = pack2(d.z, d.w);
            }
            __syncthreads();
#pragma unroll
            for (int j = 0; j < 12; j++) {
                int idx = tid + j * 512;            // 6144 = 64m * 96c
                int mm = idx / 96, cc = idx % 96;
                As[h][mm * 200 + cg * 96 + cc] = scratchS[cc * 70 + mm];
            }
        }
    }

    int wave = tid >> 6, lane = tid & 63;
    int h = wave >> 2, w4 = wave & 3;
    int mb = (w4 >> 1) * 32, ob = (w4 & 1) * 32;
    int lrow = lane & 15, lk = lane >> 4;
    const ushort* myAs = As[h];
    int mglob = m0 + h * 64;

    // ---- loop over 9 o-tiles ----
    for (int oi = 0; oi < 9; oi++) {
        int o0 = oi * 64;
        __syncthreads();               // scratch reads / prev MFMA Bs reads done
#pragma unroll
        for (int j = 0; j < 3; j++) {
            int chunk = tid + j * 512;          // 1536 = 64 rows * 24 uint4
            int r = chunk / 24, c8 = chunk % 24;
            *(uint4*)&Bs[r * 200 + c8 * 8] =
                *(const uint4*)(Wbf + (size_t)(o0 + r) * C_ + c8 * 8);
        }
        if (tid < 64) biasS[tid] = bias[o0 + tid];
        __syncthreads();

        f32x4 acc[2][2];
#pragma unroll
        for (int i = 0; i < 2; i++)
#pragma unroll
            for (int j = 0; j < 2; j++) acc[i][j] = (f32x4){0.f, 0.f, 0.f, 0.f};

#pragma unroll
        for (int ks = 0; ks < 6; ks++) {
            bf16x8 a[2], b[2];
#pragma unroll
            for (int mt = 0; mt < 2; mt++)
                a[mt] = *(const bf16x8*)&myAs[(mb + mt * 16 + lrow) * 200 + ks * 32 + lk * 8];
#pragma unroll
            for (int ot = 0; ot < 2; ot++)
                b[ot] = *(const bf16x8*)&Bs[(ob + ot * 16 + lrow) * 200 + ks * 32 + lk * 8];
#pragma unroll
            for (int mt = 0; mt < 2; mt++)
#pragma unroll
                for (int ot = 0; ot < 2; ot++)
                    acc[mt][ot] = MFMA16(a[mt], b[ot], acc[mt][ot]);
        }

        ushort* op = qkvT + ((size_t)n * TV + mglob) * C3 + o0;
#pragma unroll
        for (int mt = 0; mt < 2; mt++) {
#pragma unroll
            for (int ot = 0; ot < 2; ot++) {
                int o = ob + ot * 16 + lrow;
                float bv = biasS[o];
#pragma unroll
                for (int r = 0; r < 4; r++) {
                    int m = mb + mt * 16 + lk * 4 + r;
                    op[(size_t)m * C3 + o] = f2bf(acc[mt][ot][r] + bv);
                }
            }
        }
    }
}

// ---------------------------------------------------------------------------
// K2p: partial[((n*3+s)*16+tc)][u][v] = sum over 8 t's of q.k  (fp32)
// grid (16,3,64) = 3072 blocks; each wave handles 2 t's independently.
// ---------------------------------------------------------------------------
__global__ __launch_bounds__(256) void k2_att(const ushort* __restrict__ qkvT,
                                              float* __restrict__ partial) {
    int tc = blockIdx.x, s = blockIdx.y, n = blockIdx.z;
    __shared__ ushort tiles[4 * 2 * 32 * 72];   // [wave][q/k][32 rows][64+8]
    __shared__ float red[4 * 32 * 33];
    int tid = threadIdx.x, wave = tid >> 6, lane = tid & 63;
    ushort* myQ = &tiles[wave * 2 * 2304];
    ushort* myK = myQ + 2304;

    // zero pad rows 25..31 of both tiles (never written again)
    if (lane < 63) {
        *(uint4*)&myQ[1800 + lane * 8] = (uint4){0, 0, 0, 0};
        *(uint4*)&myK[1800 + lane * 8] = (uint4){0, 0, 0, 0};
    }

    const size_t nbase = (size_t)n * TV * C3;
    int qoff = s * MID;
    int koff = C_ + s * MID;
    int lrow = lane & 15, lk = lane >> 4;

    f32x4 acc[2][2];
#pragma unroll
    for (int i = 0; i < 2; i++)
#pragma unroll
        for (int j = 0; j < 2; j++) acc[i][j] = (f32x4){0.f, 0.f, 0.f, 0.f};

#pragma unroll
    for (int i = 0; i < 2; i++) {
        int t = tc * 8 + wave + 4 * i;
#pragma unroll
        for (int j = 0; j < 7; j++) {
            int idx = lane + j * 64;
            if (idx < 400) {
                int op = idx / 200, rr = idx % 200;
                int row = rr >> 3, c16 = rr & 7;
                int chan = (op ? koff : qoff) + c16 * 8;
                uint4 d = *(const uint4*)(qkvT + nbase + (size_t)(t * V_ + row) * C3 + chan);
                *(uint4*)((op ? myK : myQ) + row * 72 + c16 * 8) = d;
            }
        }
#pragma unroll
        for (int ks = 0; ks < 2; ks++) {
            bf16x8 a0 = *(const bf16x8*)&myQ[lrow * 72 + ks * 32 + lk * 8];
            bf16x8 a1 = *(const bf16x8*)&myQ[(16 + lrow) * 72 + ks * 32 + lk * 8];
            bf16x8 b0 = *(const bf16x8*)&myK[lrow * 72 + ks * 32 + lk * 8];
            bf16x8 b1 = *(const bf16x8*)&myK[(16 + lrow) * 72 + ks * 32 + lk * 8];
            acc[0][0] = MFMA16(a0, b0, acc[0][0]);
            acc[0][1] = MFMA16(a0, b1, acc[0][1]);
            acc[1][0] = MFMA16(a1, b0, acc[1][0]);
            acc[1][1] = MFMA16(a1, b1, acc[1][1]);
        }
    }

#pragma unroll
    for (int ub = 0; ub < 2; ub++)
#pragma unroll
        for (int vb = 0; vb < 2; vb++)
#pragma unroll
            for (int r = 0; r < 4; r++) {
                int u = ub * 16 + lk * 4 + r, v = vb * 16 + lrow;
                red[wave * 1056 + u * 33 + v] = acc[ub][vb][r];
            }
    __syncthreads();

    float* pb = partial + (((size_t)n * S_ + s) * NCHUNK + tc) * PSTRIDE;
    for (int idx = tid; idx < 1024; idx += 256) {
        int u = idx >> 5, v = idx & 31;
        if (u < V_ && v < V_) {
            float sum = red[u * 33 + v] + red[1056 + u * 33 + v] +
                        red[2112 + u * 33 + v] + red[3168 + u * 33 + v];
            pb[u * V_ + v] = sum;
        }
    }
}

// ---------------------------------------------------------------------------
// K2r: attOut[ns][r] = tanh(sum_j partial[ns][j][r] / 8192)
// ---------------------------------------------------------------------------
__global__ __launch_bounds__(256) void k2_reduce(const float* __restrict__ partial,
                                                 float* __restrict__ attOut) {
    int idx = blockIdx.x * 256 + threadIdx.x;
    if (idx >= 192 * 625) return;
    int ns = idx / 625, r = idx % 625;
    const float* p = partial + (size_t)ns * NCHUNK * PSTRIDE + r;
    float s = 0.f;
#pragma unroll
    for (int j = 0; j < NCHUNK; j++) s += p[j * PSTRIDE];
    attOut[(size_t)ns * 625 + r] = tanhf(s * (1.0f / 8192.0f));
}

// ---------------------------------------------------------------------------
// K3: yT[n][t*25+u][c'] = sum_v att[n][s(c')][u][v] * qkv_v[n][t*25+v][c']
// ---------------------------------------------------------------------------
__global__ __launch_bounds__(192) void k3_y(const ushort* __restrict__ qkvT,
                                            const float* __restrict__ attF,
                                            ushort* __restrict__ yT) {
    int t = blockIdx.x, n = blockIdx.y;
    __shared__ float attS[3 * 700];   // [s][u][28 pad]
    int tid = threadIdx.x;
    const float* ab = attF + (size_t)n * (S_ * V_ * V_);
    for (int idx = tid; idx < S_ * V_ * V_; idx += 192) {
        int s = idx / 625, r = idx % 625;
        attS[s * 700 + (r / 25) * 28 + (r % 25)] = ab[idx];
    }
    __syncthreads();

    int c = tid;
    int s = c >> 6;
    const ushort* vb = qkvT + ((size_t)n * TV + (size_t)t * V_) * C3 + 2 * C_ + c;
    float vreg[25];
#pragma unroll
    for (int v = 0; v < 25; v++) vreg[v] = bf2f(vb[(size_t)v * C3]);

    ushort* yb = yT + ((size_t)n * TV + (size_t)t * V_) * C_ + c;
    const float* as = &attS[s * 700];
    for (int u = 0; u < 25; u++) {
        float a = 0.f;
#pragma unroll
        for (int v = 0; v < 25; v++) a += as[u * 28 + v] * vreg[v];
        yb[(size_t)u * C_] = f2bf(a);
    }
}

// ---------------------------------------------------------------------------
// K4: out[n][o][m] = LeakyReLU(x + (yT.Wff^T)*inv[o] + shift[o], 0.1)  fp32
// m-tile 64, A staged once, 3 o-tiles; B staged per tile from bf16 WffB
// (6 uint4 copies, no conversion). zT aliases Bs -> LDS ~51.5KB, 3 blocks/CU.
// LDS-transposed fp32 epilogue with float4 stores.  (R2-verified version.)
// ---------------------------------------------------------------------------
__global__ __launch_bounds__(256) void k4_out(const ushort* __restrict__ yT,
                                              const ushort* __restrict__ Wbf,
                                              const float* __restrict__ bff,
                                              const float* __restrict__ gamma,
                                              const float* __restrict__ beta,
                                              const float* __restrict__ rmean,
                                              const float* __restrict__ rvar,
                                              const float* __restrict__ x,
                                              float* __restrict__ out) {
    int m0 = blockIdx.x * 64, n = blockIdx.y;
    __shared__ ushort As[64 * 200];
    __shared__ ushort Bs[64 * 200];    // 25.6KB; reused as fp32 zT[64][68] (17.4KB)
    __shared__ float invS[64], shiftS[64];
    float* zT = (float*)Bs;
    int tid = threadIdx.x;

    const ushort* ab = yT + ((size_t)n * TV + m0) * C_;
#pragma unroll
    for (int j = 0; j < 6; j++) {
        int chunk = tid + j * 256;          // 1536 = 64 rows * 24 chunks
        int r = chunk / 24, c8 = chunk % 24;
        *(uint4*)&As[r * 200 + c8 * 8] = *(const uint4*)(ab + (size_t)r * C_ + c8 * 8);
    }

    int wave = tid >> 6, lane = tid & 63;
    int mb = (wave >> 1) * 32, obw = (wave & 1) * 32;
    int lrow = lane & 15, lk = lane >> 4;

    for (int oi = 0; oi < 3; oi++) {
        int o0 = oi * 64;
        __syncthreads();               // As staged / prev epilogue zT reads done
#pragma unroll
        for (int j = 0; j < 6; j++) {
            int chunk = tid + j * 256;          // 1536 = 64 rows * 24 uint4
            int r = chunk / 24, c8 = chunk % 24;
            *(uint4*)&Bs[r * 200 + c8 * 8] =
                *(const uint4*)(Wbf + (size_t)(o0 + r) * C_ + c8 * 8);
        }
        if (tid < 64) {
            int o = o0 + tid;
            float inv = gamma[o] * rsqrtf(rvar[o] + 1e-5f);
            invS[tid] = inv;
            shiftS[tid] = beta[o] - rmean[o] * inv + bff[o] * inv;
        }
        __syncthreads();

        f32x4 acc[2][2];
#pragma unroll
        for (int i = 0; i < 2; i++)
#pragma unroll
            for (int j = 0; j < 2; j++) acc[i][j] = (f32x4){0.f, 0.f, 0.f, 0.f};

#pragma unroll
        for (int ks = 0; ks < 6; ks++) {
            bf16x8 a[2], b[2];
#pragma unroll
            for (int mt = 0; mt < 2; mt++)
                a[mt] = *(const bf16x8*)&As[(mb + mt * 16 + lrow) * 200 + ks * 32 + lk * 8];
#pragma unroll
            for (int ot = 0; ot < 2; ot++)
                b[ot] = *(const bf16x8*)&Bs[(obw + ot * 16 + lrow) * 200 + ks * 32 + lk * 8];
#pragma unroll
            for (int mt = 0; mt < 2; mt++)
#pragma unroll
                for (int ot = 0; ot < 2; ot++)
                    acc[mt][ot] = MFMA16(a[mt], b[ot], acc[mt][ot]);
        }

        __syncthreads();               // all waves done reading Bs (W)
#pragma unroll
        for (int mt = 0; mt < 2; mt++)
#pragma unroll
            for (int ot = 0; ot < 2; ot++) {
                int o = obw + ot * 16 + lrow;
                float inv = invS[o], sh = shiftS[o];
#pragma unroll
                for (int r = 0; r < 4; r++) {
                    int m = mb + mt * 16 + lk * 4 + r;
                    zT[o * 68 + m] = acc[mt][ot][r] * inv + sh;
                }
            }
        __syncthreads();

        const float* xb = x + ((size_t)n * C_ + o0) * TV + m0;
        float* ob2 = out + ((size_t)n * C_ + o0) * TV + m0;
#pragma unroll
        for (int j = 0; j < 4; j++) {
            int chunk = tid + j * 256;          // 1024 = 64 rows * 16 f4
            int o = chunk >> 4, m4 = chunk & 15;
            float4 zv = *(float4*)&zT[o * 68 + m4 * 4];
            float4 xv = *(const float4*)(xb + (size_t)o * TV + m4 * 4);
            float4 res; float a;
            a = xv.x + zv.x; res.x = (a >= 0.f) ? a : 0.1f * a;
            a = xv.y + zv.y; res.y = (a >= 0.f) ? a : 0.1f * a;
            a = xv.z + zv.z; res.z = (a >= 0.f) ? a : 0.1f * a;
            a = xv.w + zv.w; res.w = (a >= 0.f) ? a : 0.1f * a;
            *(float4*)(ob2 + (size_t)o * TV + m4 * 4) = res;
        }
    }
}

// ---------------------------------------------------------------------------
extern "C" void kernel_launch(void* const* d_in, const int* in_sizes, int n_in,
                              void* d_out, int out_size, void* d_ws, size_t ws_size,
                              hipStream_t stream) {
    (void)in_sizes; (void)n_in; (void)out_size; (void)ws_size;
    const float* x    = (const float*)d_in[0];
    const float* Wqkv = (const float*)d_in[1];
    const float* bqkv = (const float*)d_in[2];
    const float* Wff  = (const float*)d_in[3];
    const float* bff  = (const float*)d_in[4];
    const float* gam  = (const float*)d_in[5];
    const float* bet  = (const float*)d_in[6];
    const float* rme  = (const float*)d_in[7];
    const float* rva  = (const float*)d_in[8];
    float* out = (float*)d_out;
    float* attOut = out + OUT_ELEMS;   // fp32 att segment of the output tuple

    char* ws = (char*)d_ws;
    ushort* qkvT = (ushort*)ws;                        // 235,929,600 B
    // partial (7.86 MB) and yT (78.6 MB) alias: partial is dead before k3 runs
    float*  partial = (float*)(ws + 235929600);
    ushort* yT      = (ushort*)(ws + 235929600);
    // WqkvB aliases the partial region: written by kconv, consumed by k1,
    // clobbered only later by k2_att's partial writes.
    ushort* WqkvB   = (ushort*)(ws + 235929600);
    // WffB aliases qkvT: qkvT is dead after k3 (k4 doesn't read it).
    ushort* WffB    = (ushort*)ws;

    kconv<<<dim3(108), 256, 0, stream>>>(Wqkv, WqkvB, 27648);   // 576*192/4
    k1_qkv<<<dim3(25, 64), 512, 0, stream>>>(x, WqkvB, bqkv, qkvT);
    k2_att<<<dim3(NCHUNK, 3, 64), 256, 0, stream>>>(qkvT, partial);
    k2_reduce<<<dim3(469), 256, 0, stream>>>(partial, attOut);
    k3_y<<<dim3(128, 64), 192, 0, stream>>>(qkvT, attOut, yT);
    kconv<<<dim3(36), 256, 0, stream>>>(Wff, WffB, 9216);       // 192*192/4
    k4_out<<<dim3(50, 64), 256, 0, stream>>>(yT, WffB, bff, gam, bet, rme, rva, x, out);
}

// Round 5
// 481.284 us; speedup vs baseline: 1.4246x; 1.0370x over previous
//
#include <hip/hip_runtime.h>
#include <hip/hip_bf16.h>

typedef __attribute__((ext_vector_type(8))) short bf16x8;
typedef __attribute__((ext_vector_type(4))) float f32x4;

#define MFMA16(a, b, c) __builtin_amdgcn_mfma_f32_16x16x32_bf16((a), (b), (c), 0, 0, 0)

#define N_ 64
#define C_ 192
#define T_ 128
#define V_ 25
#define S_ 3
#define MID 64
#define TV 3200          // T_*V_
#define C3 576           // 3*C_
#define OUT_ELEMS 39321600ULL
#define NCHUNK 16        // T-chunks for k2 partials
#define PSTRIDE 640      // padded 25*25 partial stride (floats)

static __device__ __forceinline__ float bf2f(ushort u) {
    union { unsigned int i; float f; } x; x.i = ((unsigned int)u) << 16; return x.f;
}
static __device__ __forceinline__ ushort f2bf(float f) {
    union { float f; unsigned int i; } x; x.f = f;
    unsigned int r = x.i + 0x7fffu + ((x.i >> 16) & 1u);
    return (ushort)(r >> 16);
}
// HW packed f32->bf16 (v_cvt_pk_bf16_f32, RNE — bit-identical to f2bf on normals)
static __device__ __forceinline__ unsigned int packcvt(float a, float b) {
    __hip_bfloat162 h = __float22bfloat162_rn(make_float2(a, b));
    union { __hip_bfloat162 h; unsigned int u; } c; c.h = h; return c.u;
}

// ---------------------------------------------------------------------------
// kconv: fp32 -> bf16 row-major copy (weights). n4 = number of float4 chunks.
// ---------------------------------------------------------------------------
__global__ __launch_bounds__(256) void kconv(const float* __restrict__ src,
                                             ushort* __restrict__ dst, int n4) {
    int i = blockIdx.x * 256 + threadIdx.x;
    if (i < n4) {
        float4 d = *(const float4*)(src + (size_t)i * 4);
        unsigned int* o = (unsigned int*)dst + (size_t)i * 2;
        o[0] = packcvt(d.x, d.y);
        o[1] = packcvt(d.z, d.w);
    }
}

// ---------------------------------------------------------------------------
// K1: qkvT[n][m][o] = sum_k x[n][k][m] * Wqkv[o][k] + bqkv[o]   (bf16 out)
// 512-thread blocks, two 64-row m-tiles sharing one Bs. A-FRAGMENTS HOISTED
// TO REGISTERS (48 VGPR): A never changes across the 9 o-tiles, so the o-loop
// reads only B from LDS (24 -> 12 ds_read_b128/tile, the dominant LDS cost).
// Bias staged once; epilogue uses HW v_cvt_pk_bf16_f32. VGPR pinned <=128
// via __launch_bounds__(512,4) to hold 2 blocks/CU (16 waves).
// ---------------------------------------------------------------------------
__global__ __launch_bounds__(512, 4) void k1_qkv(const float* __restrict__ x,
                                                 const ushort* __restrict__ Wbf,
                                                 const float* __restrict__ bias,
                                                 ushort* __restrict__ qkvT) {
    int m0 = blockIdx.x * 128, n = blockIdx.y;
    __shared__ ushort As[2][64 * 200]; // [half][m][c], c stride 200 shorts
    __shared__ ushort Bs[64 * 200];    // [o][c]; front 13.4KB aliased as scratch
    __shared__ float biasS[C3];
    unsigned int* scratchU = (unsigned int*)Bs;   // 96 rows x 35 dwords (odd stride)
    ushort* scratchS = Bs;                        // same, short view: row stride 70
    int tid = threadIdx.x;

    for (int i = tid; i < C3; i += 512) biasS[i] = bias[i];

    // ---- stage A: 2 halves x 2 groups of 96 channels (fused f32->bf16 transpose)
    for (int h = 0; h < 2; h++) {
        for (int cg = 0; cg < 2; cg++) {
            if (h || cg) __syncthreads();  // transpose reads of scratch done
#pragma unroll
            for (int j = 0; j < 3; j++) {
                int chunk = tid + j * 512;          // 1536 = 96c * 16 f4
                int cc = chunk >> 4, m4 = chunk & 15;
                float4 d = *(const float4*)(x + ((size_t)n * C_ + cg * 96 + cc) * TV
                                            + m0 + h * 64 + m4 * 4);
                scratchU[cc * 35 + m4 * 2]     = packcvt(d.x, d.y);
                scratchU[cc * 35 + m4 * 2 + 1] = packcvt(d.z, d.w);
            }
            __syncthreads();
#pragma unroll
            for (int j = 0; j < 12; j++) {
                int idx = tid + j * 512;            // 6144 = 64m * 96c
                int mm = idx / 96, cc = idx % 96;
                As[h][mm * 200 + cg * 96 + cc] = scratchS[cc * 70 + mm];
            }
        }
    }
    __syncthreads();   // As complete -> safe to read fragments

    int wave = tid >> 6, lane = tid & 63;
    int h = wave >> 2, w4 = wave & 3;
    int mb = (w4 >> 1) * 32, ob = (w4 & 1) * 32;
    int lrow = lane & 15, lk = lane >> 4;
    const ushort* myAs = As[h];
    int mglob = m0 + h * 64;

    // ---- hoist A-fragments to registers: 12 x bf16x8 = 48 VGPR, read ONCE
    bf16x8 afrag[2][6];
#pragma unroll
    for (int ks = 0; ks < 6; ks++)
#pragma unroll
        for (int mt = 0; mt < 2; mt++)
            afrag[mt][ks] = *(const bf16x8*)&myAs[(mb + mt * 16 + lrow) * 200 + ks * 32 + lk * 8];

    // ---- loop over 9 o-tiles: LDS reads are B-only ----
    for (int oi = 0; oi < 9; oi++) {
        int o0 = oi * 64;
        __syncthreads();               // scratch/afrag reads, prev MFMA Bs reads done
#pragma unroll
        for (int j = 0; j < 3; j++) {
            int chunk = tid + j * 512;          // 1536 = 64 rows * 24 uint4
            int r = chunk / 24, c8 = chunk % 24;
            *(uint4*)&Bs[r * 200 + c8 * 8] =
                *(const uint4*)(Wbf + (size_t)(o0 + r) * C_ + c8 * 8);
        }
        __syncthreads();

        f32x4 acc[2][2];
#pragma unroll
        for (int i = 0; i < 2; i++)
#pragma unroll
            for (int j = 0; j < 2; j++) acc[i][j] = (f32x4){0.f, 0.f, 0.f, 0.f};

#pragma unroll
        for (int ks = 0; ks < 6; ks++) {
            bf16x8 b[2];
#pragma unroll
            for (int ot = 0; ot < 2; ot++)
                b[ot] = *(const bf16x8*)&Bs[(ob + ot * 16 + lrow) * 200 + ks * 32 + lk * 8];
#pragma unroll
            for (int mt = 0; mt < 2; mt++)
#pragma unroll
                for (int ot = 0; ot < 2; ot++)
                    acc[mt][ot] = MFMA16(afrag[mt][ks], b[ot], acc[mt][ot]);
        }

        ushort* op = qkvT + ((size_t)n * TV + mglob) * C3 + o0;
#pragma unroll
        for (int mt = 0; mt < 2; mt++) {
#pragma unroll
            for (int ot = 0; ot < 2; ot++) {
                int o = ob + ot * 16 + lrow;
                float bv = biasS[o0 + o];
                ushort* col = op + o;
#pragma unroll
                for (int r = 0; r < 4; r += 2) {
                    int m = mb + mt * 16 + lk * 4 + r;
                    unsigned int pk = packcvt(acc[mt][ot][r] + bv, acc[mt][ot][r + 1] + bv);
                    col[(size_t)m * C3] = (ushort)(pk & 0xffffu);
                    col[(size_t)(m + 1) * C3] = (ushort)(pk >> 16);
                }
            }
        }
    }
}

// ---------------------------------------------------------------------------
// K2p: partial[((n*3+s)*16+tc)][u][v] = sum over 8 t's of q.k  (fp32)
// grid (16,3,64) = 3072 blocks; each wave handles 2 t's independently.
// ---------------------------------------------------------------------------
__global__ __launch_bounds__(256) void k2_att(const ushort* __restrict__ qkvT,
                                              float* __restrict__ partial) {
    int tc = blockIdx.x, s = blockIdx.y, n = blockIdx.z;
    __shared__ ushort tiles[4 * 2 * 32 * 72];   // [wave][q/k][32 rows][64+8]
    __shared__ float red[4 * 32 * 33];
    int tid = threadIdx.x, wave = tid >> 6, lane = tid & 63;
    ushort* myQ = &tiles[wave * 2 * 2304];
    ushort* myK = myQ + 2304;

    // zero pad rows 25..31 of both tiles (never written again)
    if (lane < 63) {
        *(uint4*)&myQ[1800 + lane * 8] = (uint4){0, 0, 0, 0};
        *(uint4*)&myK[1800 + lane * 8] = (uint4){0, 0, 0, 0};
    }

    const size_t nbase = (size_t)n * TV * C3;
    int qoff = s * MID;
    int koff = C_ + s * MID;
    int lrow = lane & 15, lk = lane >> 4;

    f32x4 acc[2][2];
#pragma unroll
    for (int i = 0; i < 2; i++)
#pragma unroll
        for (int j = 0; j < 2; j++) acc[i][j] = (f32x4){0.f, 0.f, 0.f, 0.f};

#pragma unroll
    for (int i = 0; i < 2; i++) {
        int t = tc * 8 + wave + 4 * i;
#pragma unroll
        for (int j = 0; j < 7; j++) {
            int idx = lane + j * 64;
            if (idx < 400) {
                int op = idx / 200, rr = idx % 200;
                int row = rr >> 3, c16 = rr & 7;
                int chan = (op ? koff : qoff) + c16 * 8;
                uint4 d = *(const uint4*)(qkvT + nbase + (size_t)(t * V_ + row) * C3 + chan);
                *(uint4*)((op ? myK : myQ) + row * 72 + c16 * 8) = d;
            }
        }
#pragma unroll
        for (int ks = 0; ks < 2; ks++) {
            bf16x8 a0 = *(const bf16x8*)&myQ[lrow * 72 + ks * 32 + lk * 8];
            bf16x8 a1 = *(const bf16x8*)&myQ[(16 + lrow) * 72 + ks * 32 + lk * 8];
            bf16x8 b0 = *(const bf16x8*)&myK[lrow * 72 + ks * 32 + lk * 8];
            bf16x8 b1 = *(const bf16x8*)&myK[(16 + lrow) * 72 + ks * 32 + lk * 8];
            acc[0][0] = MFMA16(a0, b0, acc[0][0]);
            acc[0][1] = MFMA16(a0, b1, acc[0][1]);
            acc[1][0] = MFMA16(a1, b0, acc[1][0]);
            acc[1][1] = MFMA16(a1, b1, acc[1][1]);
        }
    }

#pragma unroll
    for (int ub = 0; ub < 2; ub++)
#pragma unroll
        for (int vb = 0; vb < 2; vb++)
#pragma unroll
            for (int r = 0; r < 4; r++) {
                int u = ub * 16 + lk * 4 + r, v = vb * 16 + lrow;
                red[wave * 1056 + u * 33 + v] = acc[ub][vb][r];
            }
    __syncthreads();

    float* pb = partial + (((size_t)n * S_ + s) * NCHUNK + tc) * PSTRIDE;
    for (int idx = tid; idx < 1024; idx += 256) {
        int u = idx >> 5, v = idx & 31;
        if (u < V_ && v < V_) {
            float sum = red[u * 33 + v] + red[1056 + u * 33 + v] +
                        red[2112 + u * 33 + v] + red[3168 + u * 33 + v];
            pb[u * V_ + v] = sum;
        }
    }
}

// ---------------------------------------------------------------------------
// K2r: attOut[ns][r] = tanh(sum_j partial[ns][j][r] / 8192)
// ---------------------------------------------------------------------------
__global__ __launch_bounds__(256) void k2_reduce(const float* __restrict__ partial,
                                                 float* __restrict__ attOut) {
    int idx = blockIdx.x * 256 + threadIdx.x;
    if (idx >= 192 * 625) return;
    int ns = idx / 625, r = idx % 625;
    const float* p = partial + (size_t)ns * NCHUNK * PSTRIDE + r;
    float s = 0.f;
#pragma unroll
    for (int j = 0; j < NCHUNK; j++) s += p[j * PSTRIDE];
    attOut[(size_t)ns * 625 + r] = tanhf(s * (1.0f / 8192.0f));
}

// ---------------------------------------------------------------------------
// K3: yT[n][t*25+u][c'] = sum_v att[n][s(c')][u][v] * qkv_v[n][t*25+v][c']
// ---------------------------------------------------------------------------
__global__ __launch_bounds__(192) void k3_y(const ushort* __restrict__ qkvT,
                                            const float* __restrict__ attF,
                                            ushort* __restrict__ yT) {
    int t = blockIdx.x, n = blockIdx.y;
    __shared__ float attS[3 * 700];   // [s][u][28 pad]
    int tid = threadIdx.x;
    const float* ab = attF + (size_t)n * (S_ * V_ * V_);
    for (int idx = tid; idx < S_ * V_ * V_; idx += 192) {
        int s = idx / 625, r = idx % 625;
        attS[s * 700 + (r / 25) * 28 + (r % 25)] = ab[idx];
    }
    __syncthreads();

    int c = tid;
    int s = c >> 6;
    const ushort* vb = qkvT + ((size_t)n * TV + (size_t)t * V_) * C3 + 2 * C_ + c;
    float vreg[25];
#pragma unroll
    for (int v = 0; v < 25; v++) vreg[v] = bf2f(vb[(size_t)v * C3]);

    ushort* yb = yT + ((size_t)n * TV + (size_t)t * V_) * C_ + c;
    const float* as = &attS[s * 700];
    for (int u = 0; u < 25; u++) {
        float a = 0.f;
#pragma unroll
        for (int v = 0; v < 25; v++) a += as[u * 28 + v] * vreg[v];
        yb[(size_t)u * C_] = f2bf(a);
    }
}

// ---------------------------------------------------------------------------
// K4: out[n][o][m] = LeakyReLU(x + (yT.Wff^T)*inv[o] + shift[o], 0.1)  fp32
// m-tile 64, A staged once + A-FRAGMENTS HOISTED TO REGISTERS (o-loop reads
// only B from LDS). BN constants hoisted out of the loop. zT aliases Bs ->
// LDS ~51.5KB, 3 blocks/CU (VGPR <=170 via launch_bounds(256,3)).
// ---------------------------------------------------------------------------
__global__ __launch_bounds__(256, 3) void k4_out(const ushort* __restrict__ yT,
                                                 const ushort* __restrict__ Wbf,
                                                 const float* __restrict__ bff,
                                                 const float* __restrict__ gamma,
                                                 const float* __restrict__ beta,
                                                 const float* __restrict__ rmean,
                                                 const float* __restrict__ rvar,
                                                 const float* __restrict__ x,
                                                 float* __restrict__ out) {
    int m0 = blockIdx.x * 64, n = blockIdx.y;
    __shared__ ushort As[64 * 200];
    __shared__ ushort Bs[64 * 200];    // 25.6KB; reused as fp32 zT[64][68] (17.4KB)
    __shared__ float invS[C_], shiftS[C_];
    float* zT = (float*)Bs;
    int tid = threadIdx.x;

    const ushort* ab = yT + ((size_t)n * TV + m0) * C_;
#pragma unroll
    for (int j = 0; j < 6; j++) {
        int chunk = tid + j * 256;          // 1536 = 64 rows * 24 chunks
        int r = chunk / 24, c8 = chunk % 24;
        *(uint4*)&As[r * 200 + c8 * 8] = *(const uint4*)(ab + (size_t)r * C_ + c8 * 8);
    }
    if (tid < C_) {
        float inv = gamma[tid] * rsqrtf(rvar[tid] + 1e-5f);
        invS[tid] = inv;
        shiftS[tid] = beta[tid] - rmean[tid] * inv + bff[tid] * inv;
    }
    __syncthreads();   // As complete -> safe to read fragments

    int wave = tid >> 6, lane = tid & 63;
    int mb = (wave >> 1) * 32, obw = (wave & 1) * 32;
    int lrow = lane & 15, lk = lane >> 4;

    // hoist A-fragments to registers (48 VGPR), read ONCE
    bf16x8 afrag[2][6];
#pragma unroll
    for (int ks = 0; ks < 6; ks++)
#pragma unroll
        for (int mt = 0; mt < 2; mt++)
            afrag[mt][ks] = *(const bf16x8*)&As[(mb + mt * 16 + lrow) * 200 + ks * 32 + lk * 8];

    for (int oi = 0; oi < 3; oi++) {
        int o0 = oi * 64;
        __syncthreads();               // afrag reads / prev epilogue zT reads done
#pragma unroll
        for (int j = 0; j < 6; j++) {
            int chunk = tid + j * 256;          // 1536 = 64 rows * 24 uint4
            int r = chunk / 24, c8 = chunk % 24;
            *(uint4*)&Bs[r * 200 + c8 * 8] =
                *(const uint4*)(Wbf + (size_t)(o0 + r) * C_ + c8 * 8);
        }
        __syncthreads();

        f32x4 acc[2][2];
#pragma unroll
        for (int i = 0; i < 2; i++)
#pragma unroll
            for (int j = 0; j < 2; j++) acc[i][j] = (f32x4){0.f, 0.f, 0.f, 0.f};

#pragma unroll
        for (int ks = 0; ks < 6; ks++) {
            bf16x8 b[2];
#pragma unroll
            for (int ot = 0; ot < 2; ot++)
                b[ot] = *(const bf16x8*)&Bs[(obw + ot * 16 + lrow) * 200 + ks * 32 + lk * 8];
#pragma unroll
            for (int mt = 0; mt < 2; mt++)
#pragma unroll
                for (int ot = 0; ot < 2; ot++)
                    acc[mt][ot] = MFMA16(afrag[mt][ks], b[ot], acc[mt][ot]);
        }

        __syncthreads();               // all waves done reading Bs (W)
#pragma unroll
        for (int mt = 0; mt < 2; mt++)
#pragma unroll
            for (int ot = 0; ot < 2; ot++) {
                int o = obw + ot * 16 + lrow;
                float inv = invS[o0 + o], sh = shiftS[o0 + o];
#pragma unroll
                for (int r = 0; r < 4; r++) {
                    int m = mb + mt * 16 + lk * 4 + r;
                    zT[o * 68 + m] = acc[mt][ot][r] * inv + sh;
                }
            }
        __syncthreads();

        const float* xb = x + ((size_t)n * C_ + o0) * TV + m0;
        float* ob2 = out + ((size_t)n * C_ + o0) * TV + m0;
#pragma unroll
        for (int j = 0; j < 4; j++) {
            int chunk = tid + j * 256;          // 1024 = 64 rows * 16 f4
            int o = chunk >> 4, m4 = chunk & 15;
            float4 zv = *(float4*)&zT[o * 68 + m4 * 4];
            float4 xv = *(const float4*)(xb + (size_t)o * TV + m4 * 4);
            float4 res; float a;
            a = xv.x + zv.x; res.x = (a >= 0.f) ? a : 0.1f * a;
            a = xv.y + zv.y; res.y = (a >= 0.f) ? a : 0.1f * a;
            a = xv.z + zv.z; res.z = (a >= 0.f) ? a : 0.1f * a;
            a = xv.w + zv.w; res.w = (a >= 0.f) ? a : 0.1f * a;
            *(float4*)(ob2 + (size_t)o * TV + m4 * 4) = res;
        }
    }
}

// ---------------------------------------------------------------------------
extern "C" void kernel_launch(void* const* d_in, const int* in_sizes, int n_in,
                              void* d_out, int out_size, void* d_ws, size_t ws_size,
                              hipStream_t stream) {
    (void)in_sizes; (void)n_in; (void)out_size; (void)ws_size;
    const float* x    = (const float*)d_in[0];
    const float* Wqkv = (const float*)d_in[1];
    const float* bqkv = (const float*)d_in[2];
    const float* Wff  = (const float*)d_in[3];
    const float* bff  = (const float*)d_in[4];
    const float* gam  = (const float*)d_in[5];
    const float* bet  = (const float*)d_in[6];
    const float* rme  = (const float*)d_in[7];
    const float* rva  = (const float*)d_in[8];
    float* out = (float*)d_out;
    float* attOut = out + OUT_ELEMS;   // fp32 att segment of the output tuple

    char* ws = (char*)d_ws;
    ushort* qkvT = (ushort*)ws;                        // 235,929,600 B
    // partial (7.86 MB) and yT (78.6 MB) alias: partial is dead before k3 runs
    float*  partial = (float*)(ws + 235929600);
    ushort* yT      = (ushort*)(ws + 235929600);
    // WqkvB aliases the partial region: written by kconv, consumed by k1,
    // clobbered only later by k2_att's partial writes.
    ushort* WqkvB   = (ushort*)(ws + 235929600);
    // WffB aliases qkvT: qkvT is dead after k3 (k4 doesn't read it).
    ushort* WffB    = (ushort*)ws;

    kconv<<<dim3(108), 256, 0, stream>>>(Wqkv, WqkvB, 27648);   // 576*192/4
    k1_qkv<<<dim3(25, 64), 512, 0, stream>>>(x, WqkvB, bqkv, qkvT);
    k2_att<<<dim3(NCHUNK, 3, 64), 256, 0, stream>>>(qkvT, partial);
    k2_reduce<<<dim3(469), 256, 0, stream>>>(partial, attOut);
    k3_y<<<dim3(128, 64), 192, 0, stream>>>(qkvT, attOut, yT);
    kconv<<<dim3(36), 256, 0, stream>>>(Wff, WffB, 9216);       // 192*192/4
    k4_out<<<dim3(50, 64), 256, 0, stream>>>(yT, WffB, bff, gam, bet, rme, rva, x, out);
}